// Round 11
// baseline (655.692 us; speedup 1.0000x reference)
//
#include <hip/hip_runtime.h>

#define T_SEQ 4096
#define D_EMB 768
#define N_HEAD 12
#define D_HEAD 64
#define D_MLP 3072
#define NTOK 8192   // B*T
#define QSCALE 0.18033688011112043f  // log2(e)/8, folded into Q at qkv epilogue

typedef __bf16 v8bf __attribute__((ext_vector_type(8)));
typedef float v4f __attribute__((ext_vector_type(4)));
typedef short v4s __attribute__((ext_vector_type(4)));
typedef unsigned v2u __attribute__((ext_vector_type(2)));

template <int N> struct IC { static constexpr int value = N; };

__device__ __forceinline__ unsigned short f2bf(float f) {
    unsigned int u = __float_as_uint(f);
    unsigned int r = (u + 0x7fffu + ((u >> 16) & 1u)) >> 16;
    return (unsigned short)r;
}

__device__ __forceinline__ void g2lds16(const void* g, void* l) {
    __builtin_amdgcn_global_load_lds(
        (const __attribute__((address_space(1))) void*)g,
        (__attribute__((address_space(3))) void*)l, 16, 0, 0);
}

__device__ __forceinline__ float fastrcp(float x) {
#if __has_builtin(__builtin_amdgcn_rcpf)
    return __builtin_amdgcn_rcpf(x);
#else
    return 1.f / x;
#endif
}

// row-swap primitives (gfx950): 32-swap gathers half-pairs, 16-swap gathers
// even/odd 16-rows. Composed they turn the S^T C/D layout into exact K32
// A-fragments -- zero LDS traffic, full-rate VALU.
__device__ __forceinline__ void pl32swap(unsigned& a, unsigned& b) {
#if __has_builtin(__builtin_amdgcn_permlane32_swap)
    v2u r = __builtin_amdgcn_permlane32_swap(a, b, false, false);
    a = r[0]; b = r[1];
#else
    asm volatile("v_permlane32_swap_b32 %0, %1" : "+v"(a), "+v"(b));
#endif
}
__device__ __forceinline__ void pl16swap(unsigned& a, unsigned& b) {
#if __has_builtin(__builtin_amdgcn_permlane16_swap)
    v2u r = __builtin_amdgcn_permlane16_swap(a, b, false, false);
    a = r[0]; b = r[1];
#else
    asm volatile("v_permlane16_swap_b32 %0, %1" : "+v"(a), "+v"(b));
#endif
}

// chunk swizzle for 32-short (4x16B) LDS rows: 16-periodic, makes frag reads
// <=2-way bank-aliased (free) instead of 8-way (2.9x, m136)
__device__ __forceinline__ int sg(int r) { return (r ^ (r >> 2)) & 3; }

// ---------------- weight cast + transpose: fp32 [K][N] -> bf16 [N][K] --------
__global__ void tcast_kernel(const float* __restrict__ in, unsigned short* __restrict__ out,
                             int K, int N) {
    __shared__ float tile[32][33];
    int k0 = blockIdx.y * 32, n0 = blockIdx.x * 32;
    int tx = threadIdx.x, ty = threadIdx.y;
    for (int i = ty; i < 32; i += 8)
        tile[i][tx] = in[(size_t)(k0 + i) * N + n0 + tx];
    __syncthreads();
    for (int i = ty; i < 32; i += 8)
        out[(size_t)(n0 + i) * K + k0 + tx] = f2bf(tile[tx][i]);
}

// ------- V transpose, TILED: [bh][t][64] -> [bh][kt][64d][64k] (8KB tiles) ---
__global__ void vtrans_kernel(const unsigned short* __restrict__ in,
                              unsigned short* __restrict__ out) {
    __shared__ unsigned short tile[32][33];
    size_t base = (size_t)blockIdx.z * T_SEQ * D_HEAD;
    int t0 = blockIdx.x * 32, d0 = blockIdx.y * 32;
    int tx = threadIdx.x, ty = threadIdx.y;
    for (int i = ty; i < 32; i += 8)
        tile[i][tx] = in[base + (size_t)(t0 + i) * D_HEAD + d0 + tx];
    __syncthreads();
    size_t tbase = base + (size_t)(t0 >> 6) * 4096 + (t0 & 32);
    for (int i = ty; i < 32; i += 8)
        out[tbase + (size_t)(d0 + i) * 64 + tx] = tile[tx][i];
}

// ---------------- LayerNorm (768 wide), fp32 in -> bf16 out ------------------
__global__ __launch_bounds__(256) void ln_kernel(const float* __restrict__ x,
                                                 const float* __restrict__ g,
                                                 const float* __restrict__ bta,
                                                 unsigned short* __restrict__ out) {
    int row = blockIdx.x;
    const float* xr = x + (size_t)row * D_EMB;
    int tid = threadIdx.x;
    float v[3];
    float s = 0.f, s2 = 0.f;
#pragma unroll
    for (int i = 0; i < 3; i++) {
        v[i] = xr[tid + i * 256];
        s += v[i];
        s2 += v[i] * v[i];
    }
#pragma unroll
    for (int o = 1; o < 64; o <<= 1) {
        s += __shfl_xor(s, o);
        s2 += __shfl_xor(s2, o);
    }
    __shared__ float red[8];
    int wave = tid >> 6, lane = tid & 63;
    if (lane == 0) { red[wave] = s; red[wave + 4] = s2; }
    __syncthreads();
    s = red[0] + red[1] + red[2] + red[3];
    s2 = red[4] + red[5] + red[6] + red[7];
    float mu = s * (1.f / 768.f);
    float var = s2 * (1.f / 768.f) - mu * mu;
    float rstd = rsqrtf(var + 1e-5f);
#pragma unroll
    for (int i = 0; i < 3; i++) {
        int c = tid + i * 256;
        out[(size_t)row * D_EMB + c] = f2bf((v[i] - mu) * rstd * g[c] + bta[c]);
    }
}

// -------- WIDE GEMM (qkv/w1): 512 thr, 8 waves (2M x 4N), 128x256 tile -------
// R11: apply R9's "more waves share one staging" to the fat GEMMs. One A
// staging (16KB dbuf) serves 8 waves; B dbuf 32KB; 48KB total -> exactly
// 3 blocks/CU (launch_bounds(512,6) pins VGPR<=85, 24 waves/CU). w1 grid
// 768 = single generation, zero tail (was 1280+256 two-gen); block-steps/CU
// halve; A-panel HBM refetch halves. Per-wave inner loop identical to the
// proven 128x128 kernel (4 wf x 4 af x 16 MFMA, sg-swizzled frags).
template <int EPI>
__global__ __launch_bounds__(512, 6) void gemm_wide_kernel(
    const unsigned short* __restrict__ A, const unsigned short* __restrict__ Bt, int K,
    int Nt, const float* __restrict__ bias, unsigned short* __restrict__ outB,
    unsigned short* __restrict__ Qb, unsigned short* __restrict__ Kb,
    unsigned short* __restrict__ Vb) {
    __shared__ unsigned short As[2][4096];   // 128 x 32
    __shared__ unsigned short Bs[2][8192];   // 256 x 32
    const int tid = threadIdx.x;
    const int wave = tid >> 6, lane = tid & 63;
    const int n16 = lane & 15, kq = lane >> 4;
    const int moff = (wave >> 2) * 64, noff = (wave & 3) * 64;
    const int id = blockIdx.x;
    const int xcd = id & 7, s = id >> 3;
    const int mt = xcd * 8 + s / Nt, nt_ = s % Nt;   // 8 M-tiles per XCD stripe
    const long m0 = (long)mt * 128, nb0 = (long)nt_ * 256;

    // staging thread-constants (1 A-chunk + 2 B-chunks per thread)
    const int rA = tid >> 2;
    const unsigned short* aP = A + (m0 + rA) * K + (((tid & 3) ^ sg(rA)) << 3);
    const unsigned short* bP0 = Bt + (nb0 + rA) * K + (((tid & 3) ^ sg(rA)) << 3);
    const int cB1 = tid + 512, rB1 = cB1 >> 2;
    const unsigned short* bP1 = Bt + (nb0 + rB1) * K + (((cB1 & 3) ^ sg(rB1)) << 3);
    // fragment LDS short-indices (sg is 16-periodic)
    const int sn = sg(n16);
    const int fw = (noff + n16) * 32 + ((kq ^ sn) << 3);
    const int fa = (moff + n16) * 32 + ((kq ^ sn) << 3);

    const v4f vzero = {0.f, 0.f, 0.f, 0.f};
    v4f acc[4][4];
#pragma unroll
    for (int wi = 0; wi < 4; wi++)
#pragma unroll
        for (int ai = 0; ai < 4; ai++) acc[wi][ai] = vzero;

    auto stage = [&](auto BUFC, int kpos) {
        constexpr int nb = decltype(BUFC)::value;
        g2lds16(aP + kpos, &As[nb][wave * 512]);
        g2lds16(bP0 + kpos, &Bs[nb][wave * 512]);
        g2lds16(bP1 + kpos, &Bs[nb][4096 + wave * 512]);
    };
    auto gstep = [&](auto BUFC, int kpos, bool pref) {
        constexpr int buf = decltype(BUFC)::value;
        __syncthreads();
        if (pref) stage(IC<buf ^ 1>{}, kpos + 32);
        v8bf wf[4], af[4];
#pragma unroll
        for (int i = 0; i < 4; i++) wf[i] = *(const v8bf*)(&Bs[buf][fw + i * 512]);
#pragma unroll
        for (int i = 0; i < 4; i++) af[i] = *(const v8bf*)(&As[buf][fa + i * 512]);
#pragma unroll
        for (int wi = 0; wi < 4; wi++)
#pragma unroll
            for (int ai = 0; ai < 4; ai++)
                acc[wi][ai] = __builtin_amdgcn_mfma_f32_16x16x32_bf16(wf[wi], af[ai],
                                                                     acc[wi][ai], 0, 0, 0);
    };

    stage(IC<0>{}, 0);
#pragma unroll 1
    for (int k0 = 0; k0 < K; k0 += 64) {
        gstep(IC<0>{}, k0, true);
        gstep(IC<1>{}, k0 + 32, k0 + 64 < K);
    }

#pragma unroll
    for (int wi = 0; wi < 4; wi++) {
#pragma unroll
        for (int ai = 0; ai < 4; ai++) {
            const long Nb = nb0 + noff + wi * 16 + kq * 4;
            const long M = m0 + moff + ai * 16 + n16;
            if (EPI == 0) {
                int which = (int)(Nb / 768);
                int c = (int)(Nb - which * 768);
                int hh = c >> 6, ii = c & 63;
                int bb = (int)(M >> 12), t = (int)(M & 4095);
                size_t dst = (((size_t)bb * N_HEAD + hh) * T_SEQ + t) * D_HEAD + ii;
                union { uint2 u2; unsigned short us[4]; } pk;
#pragma unroll
                for (int r = 0; r < 4; r++) {
                    float v = acc[wi][ai][r];
                    if (which == 0) v *= QSCALE;
                    pk.us[r] = f2bf(v);
                }
                if (which == 0) *(uint2*)(&Qb[dst]) = pk.u2;
                else if (which == 1) *(uint2*)(&Kb[dst]) = pk.u2;
                else *(uint2*)(&Vb[dst]) = pk.u2;
            } else {
                float4 b4 = *(const float4*)(&bias[Nb]);
                union { uint2 u2; unsigned short us[4]; } pk;
#pragma unroll
                for (int r = 0; r < 4; r++) {
                    float t = acc[wi][ai][r] + ((const float*)&b4)[r];
                    // tanh-form GELU via exp2+rcp (~7 VALU vs erff ~40)
                    float y = t * (-2.302118131f + t * t * -0.1029433585f);
                    float gl = t * fastrcp(1.f + __builtin_amdgcn_exp2f(y));
                    pk.us[r] = f2bf(gl);
                }
                *(uint2*)(&outB[M * 3072 + Nb]) = pk.u2;
            }
        }
    }
}

// -------- split-K GEMM for thin-N (wo/w2): 512 thr, 2 K-groups, EPI=1 --------
// R8-proven: same tile + grid, waves 0-3 K-half 0 / waves 4-7 K-half 1 (own
// LDS staging, 64KB); steps/block halve, chains/CU double. Group-1 accs pass
// through the dead staging LDS; group-0 adds + bias/resid epilogue.
__global__ __launch_bounds__(512, 4) void gemm_splitk_kernel(
    const unsigned short* __restrict__ A, const unsigned short* __restrict__ Bt, int K,
    int Nt, const float* __restrict__ bias, const float* __restrict__ resid,
    float* __restrict__ outF) {
    __shared__ __align__(16) unsigned short SH[32768];   // 64KB
    const int tid = threadIdx.x;
    const int wave = tid >> 6, lane = tid & 63;
    const int kg = wave >> 2, wv = wave & 3;
    const int n16 = lane & 15, kq = lane >> 4;
    const int moff = (wv >> 1) * 64, noff = (wv & 1) * 64;
    const int id = blockIdx.x;
    const int xcd = id & 7, s = id >> 3;
    const int mt = xcd * (NTOK / 128 / 8) + s / Nt, nt_ = s % Nt;
    const long m0 = (long)mt * 128, nb0 = (long)nt_ * 128;
    const int Kh = K >> 1;

    const int c0 = (wv * 2 + 0) * 64 + lane;
    const int c1 = (wv * 2 + 1) * 64 + lane;
    const int r0 = c0 >> 2, r1 = c1 >> 2;
    const int kb = kg * Kh;
    const unsigned short* bP0 = Bt + (nb0 + r0) * K + ((((c0 & 3) ^ sg(r0)) << 3) + kb);
    const unsigned short* bP1 = Bt + (nb0 + r1) * K + ((((c1 & 3) ^ sg(r1)) << 3) + kb);
    const unsigned short* aP0 = A + (m0 + r0) * K + ((((c0 & 3) ^ sg(r0)) << 3) + kb);
    const unsigned short* aP1 = A + (m0 + r1) * K + ((((c1 & 3) ^ sg(r1)) << 3) + kb);
    const int sn = sg(n16);
    const int fw = (noff + n16) * 32 + ((kq ^ sn) << 3);
    const int fa = (moff + n16) * 32 + ((kq ^ sn) << 3);
    // LDS carve (short idx): A(kg,buf) @ (kg*2+buf)*4096; B(kg,buf) @ 16384+...
    const int abase = kg * 8192, bbase = 16384 + kg * 8192;

    const v4f vzero = {0.f, 0.f, 0.f, 0.f};
    v4f acc[4][4];
#pragma unroll
    for (int wi = 0; wi < 4; wi++)
#pragma unroll
        for (int ai = 0; ai < 4; ai++) acc[wi][ai] = vzero;

    auto stage = [&](auto BUFC, int kpos) {
        constexpr int nb = decltype(BUFC)::value;
        unsigned short* asb = SH + abase + nb * 4096;
        unsigned short* bsb = SH + bbase + nb * 4096;
        g2lds16(aP0 + kpos, asb + (wv * 2 + 0) * 512);
        g2lds16(aP1 + kpos, asb + (wv * 2 + 1) * 512);
        g2lds16(bP0 + kpos, bsb + (wv * 2 + 0) * 512);
        g2lds16(bP1 + kpos, bsb + (wv * 2 + 1) * 512);
    };
    auto gstep = [&](auto BUFC, int kpos, bool pref) {
        constexpr int buf = decltype(BUFC)::value;
        __syncthreads();
        if (pref) stage(IC<buf ^ 1>{}, kpos + 32);
        const unsigned short* asb = SH + abase + buf * 4096;
        const unsigned short* bsb = SH + bbase + buf * 4096;
        v8bf wf[4], af[4];
#pragma unroll
        for (int i = 0; i < 4; i++) wf[i] = *(const v8bf*)(bsb + fw + i * 512);
#pragma unroll
        for (int i = 0; i < 4; i++) af[i] = *(const v8bf*)(asb + fa + i * 512);
#pragma unroll
        for (int wi = 0; wi < 4; wi++)
#pragma unroll
            for (int ai = 0; ai < 4; ai++)
                acc[wi][ai] = __builtin_amdgcn_mfma_f32_16x16x32_bf16(wf[wi], af[ai],
                                                                     acc[wi][ai], 0, 0, 0);
    };

    stage(IC<0>{}, 0);
#pragma unroll 1
    for (int k0 = 0; k0 < Kh; k0 += 64) {
        gstep(IC<0>{}, k0, true);
        gstep(IC<1>{}, k0 + 32, k0 + 64 < Kh);
    }

    // cross-group reduction through the (now dead) staging LDS: 4096 v4f = 64KB
    __syncthreads();                       // all frag reads of SH done
    v4f* ex = (v4f*)SH;
    if (kg == 1) {
#pragma unroll
        for (int wi = 0; wi < 4; wi++)
#pragma unroll
            for (int ai = 0; ai < 4; ai++)
                ex[((wv * 16 + wi * 4 + ai) << 6) + lane] = acc[wi][ai];
    }
    __syncthreads();
    if (kg == 1) return;

#pragma unroll
    for (int wi = 0; wi < 4; wi++) {
#pragma unroll
        for (int ai = 0; ai < 4; ai++) {
            v4f p = ex[((wv * 16 + wi * 4 + ai) << 6) + lane];
            const long Nb = nb0 + noff + wi * 16 + kq * 4;
            const long M = m0 + moff + ai * 16 + n16;
            float4 b4 = *(const float4*)(&bias[Nb]);
            float4 r4 = *(const float4*)(&resid[M * 768 + Nb]);
            float4 o4;
            o4.x = acc[wi][ai][0] + p[0] + b4.x + r4.x;
            o4.y = acc[wi][ai][1] + p[1] + b4.y + r4.y;
            o4.z = acc[wi][ai][2] + p[2] + b4.z + r4.z;
            o4.w = acc[wi][ai][3] + p[3] + b4.w + r4.w;
            *(float4*)(&outF[M * 768 + Nb]) = o4;
        }
    }
}

// ---------------- Flash attention (causal), bf16 Q/K/Vt -> bf16 y ------------
// R9-proven: 512-thread blocks, 8 waves x 16 q = 128 q-rows per block sharing
// ONE K/V staging. S^T trick, pre-scaled Q, l via ones-MFMA, P in registers
// via permlane32/16_swap -> exact K32 A-frags, setprio around MFMA clusters.
__global__ __launch_bounds__(512) void attn_kernel(const unsigned short* __restrict__ Q,
                                                   const unsigned short* __restrict__ Kg,
                                                   const unsigned short* __restrict__ Vt,
                                                   unsigned short* __restrict__ y) {
    __shared__ unsigned short Kt[2][4096];
    __shared__ unsigned short Vl[2][4096];
    const int tid = threadIdx.x;
    const int wave = tid >> 6, lane = tid & 63;
    const int n16 = lane & 15, kq = lane >> 4;
    const int id = blockIdx.x;
    const int xcd = id & 7, slot = id >> 3;           // slot 0..95
    const int combo = xcd * 3 + (slot % 3);           // 3 bh-combos per XCD
    const int qt2 = 31 - slot / 3;                    // longest blocks first
    const int h = combo % N_HEAD, b = combo / N_HEAD;
    const size_t hoff = (((size_t)b * N_HEAD + h) * T_SEQ) * D_HEAD;
    const unsigned short* Qh = Q + hoff;
    const unsigned short* Kh = Kg + hoff;   // [t][64], k-tile contiguous 8KB
    const unsigned short* Vh = Vt + hoff;   // [kt][64][64] tiled
    const v4f vzero = {0.f, 0.f, 0.f, 0.f};

    // staging: 8 waves x 1 chunk/lane per tile (512 chunks of 16B each)
    const int sC = wave * 64 + lane;
    const int soff = (sC >> 3) * 64 + ((((sC & 7) ^ ((sC >> 3) & 7))) << 3);
    const int fb0 = n16 * 64 + ((kq ^ (n16 & 7)) << 3);
    const int fb1 = n16 * 64 + (((4 + kq) ^ (n16 & 7)) << 3);
    v8bf vone;
#pragma unroll
    for (int j = 0; j < 8; j++) ((unsigned short*)&vone)[j] = 0x3F80;  // bf16 1.0

    const int qglob = qt2 * 128 + wave * 16 + n16;
    v8bf qf[2];
#pragma unroll
    for (int ks = 0; ks < 2; ks++)
        qf[ks] = *(const v8bf*)(&Qh[(size_t)qglob * D_HEAD + ks * 32 + kq * 8]);

    v4f o[4], lacc;
#pragma unroll
    for (int nt = 0; nt < 4; nt++) o[nt] = vzero;
    lacc = vzero;

    const unsigned short* knext;
    const unsigned short* vnext;

    auto step = [&](auto BUFC, int kt, bool pref, bool diag) {
        constexpr int buf = decltype(BUFC)::value;
        __syncthreads();  // buf's tiles ready (vmcnt), prev reads done (lgkm)
        if (pref) {
            g2lds16(knext + soff, &Kt[buf ^ 1][wave * 512]);
            g2lds16(vnext + soff, &Vl[buf ^ 1][wave * 512]);
            knext += 4096;
            vnext += 4096;
        }
        v4f s[4];
#pragma unroll
        for (int nt = 0; nt < 4; nt++) s[nt] = vzero;
        __builtin_amdgcn_s_setprio(1);
#pragma unroll
        for (int nt = 0; nt < 4; nt++) {
            v8bf k0 = *(const v8bf*)(&Kt[buf][nt * 1024 + fb0]);
            v8bf k1 = *(const v8bf*)(&Kt[buf][nt * 1024 + fb1]);
            s[nt] = __builtin_amdgcn_mfma_f32_16x16x32_bf16(k0, qf[0], s[nt], 0, 0, 0);
            s[nt] = __builtin_amdgcn_mfma_f32_16x16x32_bf16(k1, qf[1], s[nt], 0, 0, 0);
        }
        __builtin_amdgcn_s_setprio(0);
        // exp2 + bf16 pack; pa[ntk] = P[keys ntk*16+4kq..+3][q=n16]
        union PW { v4s s4; unsigned u[2]; } pa[4];
#pragma unroll
        for (int ntk = 0; ntk < 4; ntk++) {
            union { v4s s4; __bf16 h[4]; } pk;
#pragma unroll
            for (int r = 0; r < 4; r++) {
                float p = __builtin_amdgcn_exp2f(s[ntk][r]);
                if (diag) {
                    int key = kt * 64 + ntk * 16 + kq * 4 + r;
                    if (key > qglob) p = 0.f;
                }
                pk.h[r] = (__bf16)p;
            }
            pa[ntk].s4 = pk.s4;
        }
        // permlane exchange: build K32 A-frags pf[ks] (lane: P^T[q=n16]
        // [keys ks*32+kq*8..+7]). For word j: 32swap gathers {u01,v01}/{u23,v23},
        // 16swap gathers even/odd rows -> W_j and W_{j+2}.
        union F8 { v8bf v; unsigned u[4]; } pf[2];
#pragma unroll
        for (int ks = 0; ks < 2; ks++) {
#pragma unroll
            for (int j = 0; j < 2; j++) {
                unsigned X = pa[2 * ks].u[j], Y = pa[2 * ks + 1].u[j];
                pl32swap(X, Y);
                pl16swap(X, Y);
                pf[ks].u[j] = X;
                pf[ks].u[j + 2] = Y;
            }
        }
        __builtin_amdgcn_s_setprio(1);
#pragma unroll
        for (int ks = 0; ks < 2; ks++) {
            lacc = __builtin_amdgcn_mfma_f32_16x16x32_bf16(pf[ks].v, vone, lacc, 0, 0, 0);
#pragma unroll
            for (int nt = 0; nt < 4; nt++) {
                v8bf vb = *(const v8bf*)(&Vl[buf][nt * 1024 + (ks ? fb1 : fb0)]);
                o[nt] = __builtin_amdgcn_mfma_f32_16x16x32_bf16(pf[ks].v, vb, o[nt], 0, 0, 0);
            }
        }
        __builtin_amdgcn_s_setprio(0);
    };

    // prologue: stage kt=0 into buf0 (first step's barrier drains vmcnt)
    g2lds16(Kh + soff, &Kt[0][wave * 512]);
    g2lds16(Vh + soff, &Vl[0][wave * 512]);
    knext = Kh + 4096;
    vnext = Vh + 4096;

    const int nst = 2 * qt2 + 2;   // always even
    int kt = 0;
#pragma unroll 1
    while (kt < nst - 2) {
        step(IC<0>{}, kt, true, false);
        step(IC<1>{}, kt + 1, true, false);
        kt += 2;
    }
    step(IC<0>{}, kt, true, true);       // prefetches tile nst-1
    step(IC<1>{}, kt + 1, false, true);  // waves 0-3 fully self-masked here

    float linv[4];
#pragma unroll
    for (int r = 0; r < 4; r++) linv[r] = fastrcp(lacc[r]);
#pragma unroll
    for (int nt = 0; nt < 4; nt++)
#pragma unroll
        for (int r = 0; r < 4; r++) {
            int q = qt2 * 128 + wave * 16 + kq * 4 + r;
            float val = o[nt][r] * linv[r];
            y[((size_t)b * T_SEQ + q) * D_EMB + h * 64 + nt * 16 + n16] = f2bf(val);
        }
}

// ---------------- launch -----------------------------------------------------
extern "C" void kernel_launch(void* const* d_in, const int* in_sizes, int n_in,
                              void* d_out, int out_size, void* d_ws, size_t ws_size,
                              hipStream_t stream) {
    const float* x = (const float*)d_in[0];
    const float* ln1_g = (const float*)d_in[1];
    const float* ln1_b = (const float*)d_in[2];
    const float* wqkv_w = (const float*)d_in[3];
    const float* wo_w = (const float*)d_in[4];
    const float* wo_b = (const float*)d_in[5];
    const float* ln2_g = (const float*)d_in[6];
    const float* ln2_b = (const float*)d_in[7];
    const float* w1_w = (const float*)d_in[8];
    const float* w1_b = (const float*)d_in[9];
    const float* w2_w = (const float*)d_in[10];
    const float* w2_b = (const float*)d_in[11];
    float* out = (float*)d_out;

    char* ws = (char*)d_ws;
    size_t off = 0;
    auto alloc = [&](size_t bytes) -> void* {
        void* p = ws + off;
        off += (bytes + 255) & ~(size_t)255;
        return p;
    };
    unsigned short* xn = (unsigned short*)alloc((size_t)NTOK * D_EMB * 2);
    unsigned short* wqkvT = (unsigned short*)alloc((size_t)2304 * 768 * 2);
    unsigned short* woT = (unsigned short*)alloc((size_t)768 * 768 * 2);
    unsigned short* w1T = (unsigned short*)alloc((size_t)3072 * 768 * 2);
    unsigned short* w2T = (unsigned short*)alloc((size_t)768 * 3072 * 2);
    unsigned short* Qb = (unsigned short*)alloc((size_t)NTOK * D_EMB * 2);
    unsigned short* Kb = (unsigned short*)alloc((size_t)NTOK * D_EMB * 2);
    unsigned short* Vb = (unsigned short*)alloc((size_t)NTOK * D_EMB * 2);
    unsigned short* yb = (unsigned short*)alloc((size_t)NTOK * D_EMB * 2);
    float* res1 = (float*)alloc((size_t)NTOK * D_EMB * 4);
    unsigned short* Vtb = xn;   // V^T overlay: xn dead during attn
    unsigned short* hbuf = Qb;  // w1 out overlay: spans Qb..yb (all dead then)

    dim3 tb(32, 8);
    tcast_kernel<<<dim3(2304 / 32, 768 / 32), tb, 0, stream>>>(wqkv_w, wqkvT, 768, 2304);
    tcast_kernel<<<dim3(768 / 32, 768 / 32), tb, 0, stream>>>(wo_w, woT, 768, 768);
    tcast_kernel<<<dim3(3072 / 32, 768 / 32), tb, 0, stream>>>(w1_w, w1T, 768, 3072);
    tcast_kernel<<<dim3(768 / 32, 3072 / 32), tb, 0, stream>>>(w2_w, w2T, 3072, 768);

    ln_kernel<<<NTOK, 256, 0, stream>>>(x, ln1_g, ln1_b, xn);

    gemm_wide_kernel<0><<<576, 512, 0, stream>>>(     // 128x256, 48KB, 3/CU
        xn, wqkvT, 768, 9, nullptr, nullptr, Qb, Kb, Vb);

    vtrans_kernel<<<dim3(T_SEQ / 32, 2, 2 * N_HEAD), tb, 0, stream>>>(Vb, Vtb);

    attn_kernel<<<768, 512, 0, stream>>>(Qb, Kb, Vtb, yb);

    gemm_splitk_kernel<<<384, 512, 0, stream>>>(      // split-K=2, 64KB LDS
        yb, woT, 768, 6, wo_b, x, res1);

    ln_kernel<<<NTOK, 256, 0, stream>>>(res1, ln2_g, ln2_b, xn);

    gemm_wide_kernel<2><<<768, 512, 0, stream>>>(     // 128x256, 3/CU exact
        xn, w1T, 768, 12, w1_b, hbuf, nullptr, nullptr, nullptr);

    gemm_splitk_kernel<<<384, 512, 0, stream>>>(      // split-K=2, 64KB LDS
        hbuf, w2T, 3072, 6, w2_b, res1, out);
}

// Round 12
// 399.955 us; speedup vs baseline: 1.6394x; 1.6394x over previous
//
#include <hip/hip_runtime.h>

#define T_SEQ 4096
#define D_EMB 768
#define N_HEAD 12
#define D_HEAD 64
#define D_MLP 3072
#define NTOK 8192   // B*T
#define QSCALE 0.18033688011112043f  // log2(e)/8, folded into Q at qkv epilogue

typedef __bf16 v8bf __attribute__((ext_vector_type(8)));
typedef float v4f __attribute__((ext_vector_type(4)));
typedef short v4s __attribute__((ext_vector_type(4)));
typedef unsigned v2u __attribute__((ext_vector_type(2)));

template <int N> struct IC { static constexpr int value = N; };

__device__ __forceinline__ unsigned short f2bf(float f) {
    unsigned int u = __float_as_uint(f);
    unsigned int r = (u + 0x7fffu + ((u >> 16) & 1u)) >> 16;
    return (unsigned short)r;
}

__device__ __forceinline__ void g2lds16(const void* g, void* l) {
    __builtin_amdgcn_global_load_lds(
        (const __attribute__((address_space(1))) void*)g,
        (__attribute__((address_space(3))) void*)l, 16, 0, 0);
}

__device__ __forceinline__ float fastrcp(float x) {
#if __has_builtin(__builtin_amdgcn_rcpf)
    return __builtin_amdgcn_rcpf(x);
#else
    return 1.f / x;
#endif
}

// row-swap primitives (gfx950): 32-swap gathers half-pairs, 16-swap gathers
// even/odd 16-rows. Composed they turn the S^T C/D layout into exact K32
// A-fragments -- zero LDS traffic, full-rate VALU.
__device__ __forceinline__ void pl32swap(unsigned& a, unsigned& b) {
#if __has_builtin(__builtin_amdgcn_permlane32_swap)
    v2u r = __builtin_amdgcn_permlane32_swap(a, b, false, false);
    a = r[0]; b = r[1];
#else
    asm volatile("v_permlane32_swap_b32 %0, %1" : "+v"(a), "+v"(b));
#endif
}
__device__ __forceinline__ void pl16swap(unsigned& a, unsigned& b) {
#if __has_builtin(__builtin_amdgcn_permlane16_swap)
    v2u r = __builtin_amdgcn_permlane16_swap(a, b, false, false);
    a = r[0]; b = r[1];
#else
    asm volatile("v_permlane16_swap_b32 %0, %1" : "+v"(a), "+v"(b));
#endif
}

// chunk swizzle for 32-short (4x16B) LDS rows: 16-periodic, makes frag reads
// <=2-way bank-aliased (free) instead of 8-way (2.9x, m136)
__device__ __forceinline__ int sg(int r) { return (r ^ (r >> 2)) & 3; }

// ---------------- weight cast + transpose: fp32 [K][N] -> bf16 [N][K] --------
__global__ void tcast_kernel(const float* __restrict__ in, unsigned short* __restrict__ out,
                             int K, int N) {
    __shared__ float tile[32][33];
    int k0 = blockIdx.y * 32, n0 = blockIdx.x * 32;
    int tx = threadIdx.x, ty = threadIdx.y;
    for (int i = ty; i < 32; i += 8)
        tile[i][tx] = in[(size_t)(k0 + i) * N + n0 + tx];
    __syncthreads();
    for (int i = ty; i < 32; i += 8)
        out[(size_t)(n0 + i) * K + k0 + tx] = f2bf(tile[tx][i]);
}

// ------- V transpose, TILED: [bh][t][64] -> [bh][kt][64d][64k] (8KB tiles) ---
__global__ void vtrans_kernel(const unsigned short* __restrict__ in,
                              unsigned short* __restrict__ out) {
    __shared__ unsigned short tile[32][33];
    size_t base = (size_t)blockIdx.z * T_SEQ * D_HEAD;
    int t0 = blockIdx.x * 32, d0 = blockIdx.y * 32;
    int tx = threadIdx.x, ty = threadIdx.y;
    for (int i = ty; i < 32; i += 8)
        tile[i][tx] = in[base + (size_t)(t0 + i) * D_HEAD + d0 + tx];
    __syncthreads();
    size_t tbase = base + (size_t)(t0 >> 6) * 4096 + (t0 & 32);
    for (int i = ty; i < 32; i += 8)
        out[tbase + (size_t)(d0 + i) * 64 + tx] = tile[tx][i];
}

// ---------------- LayerNorm (768 wide), fp32 in -> bf16 out ------------------
__global__ __launch_bounds__(256) void ln_kernel(const float* __restrict__ x,
                                                 const float* __restrict__ g,
                                                 const float* __restrict__ bta,
                                                 unsigned short* __restrict__ out) {
    int row = blockIdx.x;
    const float* xr = x + (size_t)row * D_EMB;
    int tid = threadIdx.x;
    float v[3];
    float s = 0.f, s2 = 0.f;
#pragma unroll
    for (int i = 0; i < 3; i++) {
        v[i] = xr[tid + i * 256];
        s += v[i];
        s2 += v[i] * v[i];
    }
#pragma unroll
    for (int o = 1; o < 64; o <<= 1) {
        s += __shfl_xor(s, o);
        s2 += __shfl_xor(s2, o);
    }
    __shared__ float red[8];
    int wave = tid >> 6, lane = tid & 63;
    if (lane == 0) { red[wave] = s; red[wave + 4] = s2; }
    __syncthreads();
    s = red[0] + red[1] + red[2] + red[3];
    s2 = red[4] + red[5] + red[6] + red[7];
    float mu = s * (1.f / 768.f);
    float var = s2 * (1.f / 768.f) - mu * mu;
    float rstd = rsqrtf(var + 1e-5f);
#pragma unroll
    for (int i = 0; i < 3; i++) {
        int c = tid + i * 256;
        out[(size_t)row * D_EMB + c] = f2bf((v[i] - mu) * rstd * g[c] + bta[c]);
    }
}

// ------------- split-K GEMM, 512 thr, 2 K-groups, 128x128 tile ---------------
// R8-proven structure, R12: now ALL four GEMMs (template EPI). Waves 0-3 do
// K-half 0, waves 4-7 K-half 1 (own LDS staging, 64KB, launch_bounds(512,4)
// -> VGPR cap 128, NO acc spill -- R11's (512,6) cap of 85 spilled acc to
// scratch: VGPR 40, 538MB WRITE, 2.5x regression). Steps/block halve and
// staging chains/CU double vs the 256-thr kernel. Group-1 accs pass through
// the dead staging LDS; group-0 adds partials + runs the epilogue.
// EPI=0: QKV scatter+QSCALE. EPI=1: bias+resid fp32. EPI=2: bias+GELU bf16.
template <int EPI>
__global__ __launch_bounds__(512, 4) void gemm_splitk_kernel(
    const unsigned short* __restrict__ A, const unsigned short* __restrict__ Bt, int K,
    int Nt, const float* __restrict__ bias, const float* __restrict__ resid,
    float* __restrict__ outF, unsigned short* __restrict__ outB,
    unsigned short* __restrict__ Qb, unsigned short* __restrict__ Kb,
    unsigned short* __restrict__ Vb) {
    __shared__ __align__(16) unsigned short SH[32768];   // 64KB
    const int tid = threadIdx.x;
    const int wave = tid >> 6, lane = tid & 63;
    const int kg = wave >> 2, wv = wave & 3;
    const int n16 = lane & 15, kq = lane >> 4;
    const int moff = (wv >> 1) * 64, noff = (wv & 1) * 64;
    const int id = blockIdx.x;
    const int xcd = id & 7, s = id >> 3;
    const int mt = xcd * 8 + s / Nt, nt_ = s % Nt;
    const long m0 = (long)mt * 128, nb0 = (long)nt_ * 128;
    const int Kh = K >> 1;

    const int c0 = (wv * 2 + 0) * 64 + lane;
    const int c1 = (wv * 2 + 1) * 64 + lane;
    const int r0 = c0 >> 2, r1 = c1 >> 2;
    const int kb = kg * Kh;
    const unsigned short* bP0 = Bt + (nb0 + r0) * K + ((((c0 & 3) ^ sg(r0)) << 3) + kb);
    const unsigned short* bP1 = Bt + (nb0 + r1) * K + ((((c1 & 3) ^ sg(r1)) << 3) + kb);
    const unsigned short* aP0 = A + (m0 + r0) * K + ((((c0 & 3) ^ sg(r0)) << 3) + kb);
    const unsigned short* aP1 = A + (m0 + r1) * K + ((((c1 & 3) ^ sg(r1)) << 3) + kb);
    const int sn = sg(n16);
    const int fw = (noff + n16) * 32 + ((kq ^ sn) << 3);
    const int fa = (moff + n16) * 32 + ((kq ^ sn) << 3);
    // LDS carve (short idx): A(kg,buf) @ (kg*2+buf)*4096; B(kg,buf) @ 16384+...
    const int abase = kg * 8192, bbase = 16384 + kg * 8192;

    const v4f vzero = {0.f, 0.f, 0.f, 0.f};
    v4f acc[4][4];
#pragma unroll
    for (int wi = 0; wi < 4; wi++)
#pragma unroll
        for (int ai = 0; ai < 4; ai++) acc[wi][ai] = vzero;

    auto stage = [&](auto BUFC, int kpos) {
        constexpr int nb = decltype(BUFC)::value;
        unsigned short* asb = SH + abase + nb * 4096;
        unsigned short* bsb = SH + bbase + nb * 4096;
        g2lds16(aP0 + kpos, asb + (wv * 2 + 0) * 512);
        g2lds16(aP1 + kpos, asb + (wv * 2 + 1) * 512);
        g2lds16(bP0 + kpos, bsb + (wv * 2 + 0) * 512);
        g2lds16(bP1 + kpos, bsb + (wv * 2 + 1) * 512);
    };
    auto gstep = [&](auto BUFC, int kpos, bool pref) {
        constexpr int buf = decltype(BUFC)::value;
        __syncthreads();
        if (pref) stage(IC<buf ^ 1>{}, kpos + 32);
        const unsigned short* asb = SH + abase + buf * 4096;
        const unsigned short* bsb = SH + bbase + buf * 4096;
        v8bf wf[4], af[4];
#pragma unroll
        for (int i = 0; i < 4; i++) wf[i] = *(const v8bf*)(bsb + fw + i * 512);
#pragma unroll
        for (int i = 0; i < 4; i++) af[i] = *(const v8bf*)(asb + fa + i * 512);
#pragma unroll
        for (int wi = 0; wi < 4; wi++)
#pragma unroll
            for (int ai = 0; ai < 4; ai++)
                acc[wi][ai] = __builtin_amdgcn_mfma_f32_16x16x32_bf16(wf[wi], af[ai],
                                                                     acc[wi][ai], 0, 0, 0);
    };

    stage(IC<0>{}, 0);
#pragma unroll 1
    for (int k0 = 0; k0 < Kh; k0 += 64) {
        gstep(IC<0>{}, k0, true);
        gstep(IC<1>{}, k0 + 32, k0 + 64 < Kh);
    }

    // cross-group reduction through the (now dead) staging LDS: 4096 v4f = 64KB
    __syncthreads();                       // all frag reads of SH done
    v4f* ex = (v4f*)SH;
    if (kg == 1) {
#pragma unroll
        for (int wi = 0; wi < 4; wi++)
#pragma unroll
            for (int ai = 0; ai < 4; ai++)
                ex[((wv * 16 + wi * 4 + ai) << 6) + lane] = acc[wi][ai];
    }
    __syncthreads();
    if (kg == 1) return;

#pragma unroll
    for (int wi = 0; wi < 4; wi++) {
#pragma unroll
        for (int ai = 0; ai < 4; ai++) {
            v4f p = ex[((wv * 16 + wi * 4 + ai) << 6) + lane];
            const long Nb = nb0 + noff + wi * 16 + kq * 4;
            const long M = m0 + moff + ai * 16 + n16;
            if (EPI == 0) {
                int which = (int)(Nb / 768);
                int c = (int)(Nb - which * 768);
                int hh = c >> 6, ii = c & 63;
                int bb = (int)(M >> 12), t = (int)(M & 4095);
                size_t dst = (((size_t)bb * N_HEAD + hh) * T_SEQ + t) * D_HEAD + ii;
                union { uint2 u2; unsigned short us[4]; } pk;
#pragma unroll
                for (int r = 0; r < 4; r++) {
                    float v = acc[wi][ai][r] + p[r];
                    if (which == 0) v *= QSCALE;
                    pk.us[r] = f2bf(v);
                }
                if (which == 0) *(uint2*)(&Qb[dst]) = pk.u2;
                else if (which == 1) *(uint2*)(&Kb[dst]) = pk.u2;
                else *(uint2*)(&Vb[dst]) = pk.u2;
            } else if (EPI == 1) {
                float4 b4 = *(const float4*)(&bias[Nb]);
                float4 r4 = *(const float4*)(&resid[M * 768 + Nb]);
                float4 o4;
                o4.x = acc[wi][ai][0] + p[0] + b4.x + r4.x;
                o4.y = acc[wi][ai][1] + p[1] + b4.y + r4.y;
                o4.z = acc[wi][ai][2] + p[2] + b4.z + r4.z;
                o4.w = acc[wi][ai][3] + p[3] + b4.w + r4.w;
                *(float4*)(&outF[M * 768 + Nb]) = o4;
            } else {
                float4 b4 = *(const float4*)(&bias[Nb]);
                union { uint2 u2; unsigned short us[4]; } pk;
#pragma unroll
                for (int r = 0; r < 4; r++) {
                    float t = acc[wi][ai][r] + p[r] + ((const float*)&b4)[r];
                    // tanh-form GELU via exp2+rcp (~7 VALU vs erff ~40)
                    float y = t * (-2.302118131f + t * t * -0.1029433585f);
                    float gl = t * fastrcp(1.f + __builtin_amdgcn_exp2f(y));
                    pk.us[r] = f2bf(gl);
                }
                *(uint2*)(&outB[M * 3072 + Nb]) = pk.u2;
            }
        }
    }
}

// ---------------- Flash attention (causal), bf16 Q/K/Vt -> bf16 y ------------
// R9-proven: 512-thread blocks, 8 waves x 16 q = 128 q-rows per block sharing
// ONE K/V staging. S^T trick, pre-scaled Q, l via ones-MFMA, P in registers
// via permlane32/16_swap -> exact K32 A-frags, setprio around MFMA clusters.
__global__ __launch_bounds__(512) void attn_kernel(const unsigned short* __restrict__ Q,
                                                   const unsigned short* __restrict__ Kg,
                                                   const unsigned short* __restrict__ Vt,
                                                   unsigned short* __restrict__ y) {
    __shared__ unsigned short Kt[2][4096];
    __shared__ unsigned short Vl[2][4096];
    const int tid = threadIdx.x;
    const int wave = tid >> 6, lane = tid & 63;
    const int n16 = lane & 15, kq = lane >> 4;
    const int id = blockIdx.x;
    const int xcd = id & 7, slot = id >> 3;           // slot 0..95
    const int combo = xcd * 3 + (slot % 3);           // 3 bh-combos per XCD
    const int qt2 = 31 - slot / 3;                    // longest blocks first
    const int h = combo % N_HEAD, b = combo / N_HEAD;
    const size_t hoff = (((size_t)b * N_HEAD + h) * T_SEQ) * D_HEAD;
    const unsigned short* Qh = Q + hoff;
    const unsigned short* Kh = Kg + hoff;   // [t][64], k-tile contiguous 8KB
    const unsigned short* Vh = Vt + hoff;   // [kt][64][64] tiled
    const v4f vzero = {0.f, 0.f, 0.f, 0.f};

    // staging: 8 waves x 1 chunk/lane per tile (512 chunks of 16B each)
    const int sC = wave * 64 + lane;
    const int soff = (sC >> 3) * 64 + ((((sC & 7) ^ ((sC >> 3) & 7))) << 3);
    const int fb0 = n16 * 64 + ((kq ^ (n16 & 7)) << 3);
    const int fb1 = n16 * 64 + (((4 + kq) ^ (n16 & 7)) << 3);
    v8bf vone;
#pragma unroll
    for (int j = 0; j < 8; j++) ((unsigned short*)&vone)[j] = 0x3F80;  // bf16 1.0

    const int qglob = qt2 * 128 + wave * 16 + n16;
    v8bf qf[2];
#pragma unroll
    for (int ks = 0; ks < 2; ks++)
        qf[ks] = *(const v8bf*)(&Qh[(size_t)qglob * D_HEAD + ks * 32 + kq * 8]);

    v4f o[4], lacc;
#pragma unroll
    for (int nt = 0; nt < 4; nt++) o[nt] = vzero;
    lacc = vzero;

    const unsigned short* knext;
    const unsigned short* vnext;

    auto step = [&](auto BUFC, int kt, bool pref, bool diag) {
        constexpr int buf = decltype(BUFC)::value;
        __syncthreads();  // buf's tiles ready (vmcnt), prev reads done (lgkm)
        if (pref) {
            g2lds16(knext + soff, &Kt[buf ^ 1][wave * 512]);
            g2lds16(vnext + soff, &Vl[buf ^ 1][wave * 512]);
            knext += 4096;
            vnext += 4096;
        }
        v4f s[4];
#pragma unroll
        for (int nt = 0; nt < 4; nt++) s[nt] = vzero;
        __builtin_amdgcn_s_setprio(1);
#pragma unroll
        for (int nt = 0; nt < 4; nt++) {
            v8bf k0 = *(const v8bf*)(&Kt[buf][nt * 1024 + fb0]);
            v8bf k1 = *(const v8bf*)(&Kt[buf][nt * 1024 + fb1]);
            s[nt] = __builtin_amdgcn_mfma_f32_16x16x32_bf16(k0, qf[0], s[nt], 0, 0, 0);
            s[nt] = __builtin_amdgcn_mfma_f32_16x16x32_bf16(k1, qf[1], s[nt], 0, 0, 0);
        }
        __builtin_amdgcn_s_setprio(0);
        // exp2 + bf16 pack; pa[ntk] = P[keys ntk*16+4kq..+3][q=n16]
        union PW { v4s s4; unsigned u[2]; } pa[4];
#pragma unroll
        for (int ntk = 0; ntk < 4; ntk++) {
            union { v4s s4; __bf16 h[4]; } pk;
#pragma unroll
            for (int r = 0; r < 4; r++) {
                float p = __builtin_amdgcn_exp2f(s[ntk][r]);
                if (diag) {
                    int key = kt * 64 + ntk * 16 + kq * 4 + r;
                    if (key > qglob) p = 0.f;
                }
                pk.h[r] = (__bf16)p;
            }
            pa[ntk].s4 = pk.s4;
        }
        // permlane exchange: build K32 A-frags pf[ks] (lane: P^T[q=n16]
        // [keys ks*32+kq*8..+7]). For word j: 32swap gathers {u01,v01}/{u23,v23},
        // 16swap gathers even/odd rows -> W_j and W_{j+2}.
        union F8 { v8bf v; unsigned u[4]; } pf[2];
#pragma unroll
        for (int ks = 0; ks < 2; ks++) {
#pragma unroll
            for (int j = 0; j < 2; j++) {
                unsigned X = pa[2 * ks].u[j], Y = pa[2 * ks + 1].u[j];
                pl32swap(X, Y);
                pl16swap(X, Y);
                pf[ks].u[j] = X;
                pf[ks].u[j + 2] = Y;
            }
        }
        __builtin_amdgcn_s_setprio(1);
#pragma unroll
        for (int ks = 0; ks < 2; ks++) {
            lacc = __builtin_amdgcn_mfma_f32_16x16x32_bf16(pf[ks].v, vone, lacc, 0, 0, 0);
#pragma unroll
            for (int nt = 0; nt < 4; nt++) {
                v8bf vb = *(const v8bf*)(&Vl[buf][nt * 1024 + (ks ? fb1 : fb0)]);
                o[nt] = __builtin_amdgcn_mfma_f32_16x16x32_bf16(pf[ks].v, vb, o[nt], 0, 0, 0);
            }
        }
        __builtin_amdgcn_s_setprio(0);
    };

    // prologue: stage kt=0 into buf0 (first step's barrier drains vmcnt)
    g2lds16(Kh + soff, &Kt[0][wave * 512]);
    g2lds16(Vh + soff, &Vl[0][wave * 512]);
    knext = Kh + 4096;
    vnext = Vh + 4096;

    const int nst = 2 * qt2 + 2;   // always even
    int kt = 0;
#pragma unroll 1
    while (kt < nst - 2) {
        step(IC<0>{}, kt, true, false);
        step(IC<1>{}, kt + 1, true, false);
        kt += 2;
    }
    step(IC<0>{}, kt, true, true);       // prefetches tile nst-1
    step(IC<1>{}, kt + 1, false, true);  // waves 0-3 fully self-masked here

    float linv[4];
#pragma unroll
    for (int r = 0; r < 4; r++) linv[r] = fastrcp(lacc[r]);
#pragma unroll
    for (int nt = 0; nt < 4; nt++)
#pragma unroll
        for (int r = 0; r < 4; r++) {
            int q = qt2 * 128 + wave * 16 + kq * 4 + r;
            float val = o[nt][r] * linv[r];
            y[((size_t)b * T_SEQ + q) * D_EMB + h * 64 + nt * 16 + n16] = f2bf(val);
        }
}

// ---------------- launch -----------------------------------------------------
extern "C" void kernel_launch(void* const* d_in, const int* in_sizes, int n_in,
                              void* d_out, int out_size, void* d_ws, size_t ws_size,
                              hipStream_t stream) {
    const float* x = (const float*)d_in[0];
    const float* ln1_g = (const float*)d_in[1];
    const float* ln1_b = (const float*)d_in[2];
    const float* wqkv_w = (const float*)d_in[3];
    const float* wo_w = (const float*)d_in[4];
    const float* wo_b = (const float*)d_in[5];
    const float* ln2_g = (const float*)d_in[6];
    const float* ln2_b = (const float*)d_in[7];
    const float* w1_w = (const float*)d_in[8];
    const float* w1_b = (const float*)d_in[9];
    const float* w2_w = (const float*)d_in[10];
    const float* w2_b = (const float*)d_in[11];
    float* out = (float*)d_out;

    char* ws = (char*)d_ws;
    size_t off = 0;
    auto alloc = [&](size_t bytes) -> void* {
        void* p = ws + off;
        off += (bytes + 255) & ~(size_t)255;
        return p;
    };
    unsigned short* xn = (unsigned short*)alloc((size_t)NTOK * D_EMB * 2);
    unsigned short* wqkvT = (unsigned short*)alloc((size_t)2304 * 768 * 2);
    unsigned short* woT = (unsigned short*)alloc((size_t)768 * 768 * 2);
    unsigned short* w1T = (unsigned short*)alloc((size_t)3072 * 768 * 2);
    unsigned short* w2T = (unsigned short*)alloc((size_t)768 * 3072 * 2);
    unsigned short* Qb = (unsigned short*)alloc((size_t)NTOK * D_EMB * 2);
    unsigned short* Kb = (unsigned short*)alloc((size_t)NTOK * D_EMB * 2);
    unsigned short* Vb = (unsigned short*)alloc((size_t)NTOK * D_EMB * 2);
    unsigned short* yb = (unsigned short*)alloc((size_t)NTOK * D_EMB * 2);
    float* res1 = (float*)alloc((size_t)NTOK * D_EMB * 4);
    unsigned short* Vtb = xn;   // V^T overlay: xn dead during attn
    unsigned short* hbuf = Qb;  // w1 out overlay: spans Qb..yb (all dead then)

    dim3 tb(32, 8);
    tcast_kernel<<<dim3(2304 / 32, 768 / 32), tb, 0, stream>>>(wqkv_w, wqkvT, 768, 2304);
    tcast_kernel<<<dim3(768 / 32, 768 / 32), tb, 0, stream>>>(wo_w, woT, 768, 768);
    tcast_kernel<<<dim3(3072 / 32, 768 / 32), tb, 0, stream>>>(w1_w, w1T, 768, 3072);
    tcast_kernel<<<dim3(768 / 32, 3072 / 32), tb, 0, stream>>>(w2_w, w2T, 3072, 768);

    ln_kernel<<<NTOK, 256, 0, stream>>>(x, ln1_g, ln1_b, xn);

    gemm_splitk_kernel<0><<<1152, 512, 0, stream>>>(  // split-K=2, 64KB LDS
        xn, wqkvT, 768, 18, nullptr, nullptr, nullptr, nullptr, Qb, Kb, Vb);

    vtrans_kernel<<<dim3(T_SEQ / 32, 2, 2 * N_HEAD), tb, 0, stream>>>(Vb, Vtb);

    attn_kernel<<<768, 512, 0, stream>>>(Qb, Kb, Vtb, yb);

    gemm_splitk_kernel<1><<<384, 512, 0, stream>>>(   // split-K=2, 64KB LDS
        yb, woT, 768, 6, wo_b, x, res1, nullptr, nullptr, nullptr, nullptr);

    ln_kernel<<<NTOK, 256, 0, stream>>>(res1, ln2_g, ln2_b, xn);

    gemm_splitk_kernel<2><<<1536, 512, 0, stream>>>(  // split-K=2, 64KB LDS
        xn, w1T, 768, 24, w1_b, nullptr, nullptr, hbuf, nullptr, nullptr, nullptr);

    gemm_splitk_kernel<1><<<384, 512, 0, stream>>>(   // split-K=2, 64KB LDS
        hbuf, w2T, 3072, 6, w2_b, res1, out, nullptr, nullptr, nullptr, nullptr);
}

// Round 13
// 395.146 us; speedup vs baseline: 1.6594x; 1.0122x over previous
//
#include <hip/hip_runtime.h>

#define T_SEQ 4096
#define D_EMB 768
#define N_HEAD 12
#define D_HEAD 64
#define D_MLP 3072
#define NTOK 8192   // B*T
#define QSCALE 0.18033688011112043f  // log2(e)/8, folded into Q at qkv epilogue

typedef __bf16 v8bf __attribute__((ext_vector_type(8)));
typedef float v4f __attribute__((ext_vector_type(4)));
typedef short v4s __attribute__((ext_vector_type(4)));
typedef unsigned v2u __attribute__((ext_vector_type(2)));

template <int N> struct IC { static constexpr int value = N; };

__device__ __forceinline__ unsigned short f2bf(float f) {
    unsigned int u = __float_as_uint(f);
    unsigned int r = (u + 0x7fffu + ((u >> 16) & 1u)) >> 16;
    return (unsigned short)r;
}

__device__ __forceinline__ void g2lds16(const void* g, void* l) {
    __builtin_amdgcn_global_load_lds(
        (const __attribute__((address_space(1))) void*)g,
        (__attribute__((address_space(3))) void*)l, 16, 0, 0);
}

__device__ __forceinline__ float fastrcp(float x) {
#if __has_builtin(__builtin_amdgcn_rcpf)
    return __builtin_amdgcn_rcpf(x);
#else
    return 1.f / x;
#endif
}

// row-swap primitives (gfx950): 32-swap gathers half-pairs, 16-swap gathers
// even/odd 16-rows. Composed they turn the S^T C/D layout into exact K32
// A-fragments -- zero LDS traffic, full-rate VALU.
__device__ __forceinline__ void pl32swap(unsigned& a, unsigned& b) {
#if __has_builtin(__builtin_amdgcn_permlane32_swap)
    v2u r = __builtin_amdgcn_permlane32_swap(a, b, false, false);
    a = r[0]; b = r[1];
#else
    asm volatile("v_permlane32_swap_b32 %0, %1" : "+v"(a), "+v"(b));
#endif
}
__device__ __forceinline__ void pl16swap(unsigned& a, unsigned& b) {
#if __has_builtin(__builtin_amdgcn_permlane16_swap)
    v2u r = __builtin_amdgcn_permlane16_swap(a, b, false, false);
    a = r[0]; b = r[1];
#else
    asm volatile("v_permlane16_swap_b32 %0, %1" : "+v"(a), "+v"(b));
#endif
}

// chunk swizzle for 32-short (4x16B) LDS rows: 16-periodic, makes frag reads
// <=2-way bank-aliased (free) instead of 8-way (2.9x, m136)
__device__ __forceinline__ int sg(int r) { return (r ^ (r >> 2)) & 3; }

// ------- merged weight cast+transpose: 4 weights in ONE launch (R13) ---------
// fp32 [K][N] -> bf16 [N][K]; flattened tile decode, saves 3 launches + tails.
__global__ void tcast4_kernel(const float* __restrict__ i0, unsigned short* __restrict__ o0,
                              const float* __restrict__ i1, unsigned short* __restrict__ o1,
                              const float* __restrict__ i2, unsigned short* __restrict__ o2,
                              const float* __restrict__ i3, unsigned short* __restrict__ o3) {
    __shared__ float tile[32][33];
    int id = blockIdx.x;
    const float* in; unsigned short* out; int K, N, t;
    if (id < 1728)      { in = i0; out = o0; K = 768;  N = 2304; t = id; }
    else if (id < 2304) { in = i1; out = o1; K = 768;  N = 768;  t = id - 1728; }
    else if (id < 4608) { in = i2; out = o2; K = 768;  N = 3072; t = id - 2304; }
    else                { in = i3; out = o3; K = 3072; N = 768;  t = id - 4608; }
    int nw = N / 32;
    int n0 = (t % nw) * 32, k0 = (t / nw) * 32;
    int tx = threadIdx.x, ty = threadIdx.y;
    for (int i = ty; i < 32; i += 8)
        tile[i][tx] = in[(size_t)(k0 + i) * N + n0 + tx];
    __syncthreads();
    for (int i = ty; i < 32; i += 8)
        out[(size_t)(n0 + i) * K + k0 + tx] = f2bf(tile[tx][i]);
}

// ---------------- LayerNorm (768 wide), fp32 in -> bf16 out ------------------
__global__ __launch_bounds__(256) void ln_kernel(const float* __restrict__ x,
                                                 const float* __restrict__ g,
                                                 const float* __restrict__ bta,
                                                 unsigned short* __restrict__ out) {
    int row = blockIdx.x;
    const float* xr = x + (size_t)row * D_EMB;
    int tid = threadIdx.x;
    float v[3];
    float s = 0.f, s2 = 0.f;
#pragma unroll
    for (int i = 0; i < 3; i++) {
        v[i] = xr[tid + i * 256];
        s += v[i];
        s2 += v[i] * v[i];
    }
#pragma unroll
    for (int o = 1; o < 64; o <<= 1) {
        s += __shfl_xor(s, o);
        s2 += __shfl_xor(s2, o);
    }
    __shared__ float red[8];
    int wave = tid >> 6, lane = tid & 63;
    if (lane == 0) { red[wave] = s; red[wave + 4] = s2; }
    __syncthreads();
    s = red[0] + red[1] + red[2] + red[3];
    s2 = red[4] + red[5] + red[6] + red[7];
    float mu = s * (1.f / 768.f);
    float var = s2 * (1.f / 768.f) - mu * mu;
    float rstd = rsqrtf(var + 1e-5f);
#pragma unroll
    for (int i = 0; i < 3; i++) {
        int c = tid + i * 256;
        out[(size_t)row * D_EMB + c] = f2bf((v[i] - mu) * rstd * g[c] + bta[c]);
    }
}

// ------------- 256-thr GEMM (w1): 128x128 tile, dbuf, 5 blk/CU ---------------
// R10-proven at 75us for w1 (R12's splitk ran 2/CU resident = 3 generations
// and regressed to 83). Swapped-operand MFMA, sg-swizzled LDS, IC<> buffers.
template <int EPI, int MT>
__global__ __launch_bounds__(256) void gemm_kernel(
    const unsigned short* __restrict__ A, const unsigned short* __restrict__ Bt, int K,
    int Nt, const float* __restrict__ bias, unsigned short* __restrict__ outB) {
    constexpr int NAI = 4;
    __shared__ unsigned short As[2][MT * 32];
    __shared__ unsigned short Bs[2][4096];
    const int tid = threadIdx.x;
    const int wave = tid >> 6, lane = tid & 63;
    const int n16 = lane & 15, kq = lane >> 4;
    const int moff = (wave >> 1) * (MT / 2), noff = (wave & 1) * 64;
    const int id = blockIdx.x;
    const int xcd = id & 7, s = id >> 3;
    const int mt = xcd * (NTOK / MT / 8) + s / Nt, nt_ = s % Nt;
    const long m0 = (long)mt * MT, nb0 = (long)nt_ * 128;

    const int c0 = (wave * 2 + 0) * 64 + lane;
    const int c1 = (wave * 2 + 1) * 64 + lane;
    const int r0 = c0 >> 2, r1 = c1 >> 2;
    const unsigned short* bP0 = Bt + (nb0 + r0) * K + (((c0 & 3) ^ sg(r0)) << 3);
    const unsigned short* bP1 = Bt + (nb0 + r1) * K + (((c1 & 3) ^ sg(r1)) << 3);
    const unsigned short* aP0 = A + (m0 + r0) * K + (((c0 & 3) ^ sg(r0)) << 3);
    const unsigned short* aP1 = A + (m0 + r1) * K + (((c1 & 3) ^ sg(r1)) << 3);
    const int sn = sg(n16);
    const int fw = (noff + n16) * 32 + ((kq ^ sn) << 3);
    const int fa = (moff + n16) * 32 + ((kq ^ sn) << 3);

    const v4f vzero = {0.f, 0.f, 0.f, 0.f};
    v4f acc[4][NAI];
#pragma unroll
    for (int wi = 0; wi < 4; wi++)
#pragma unroll
        for (int ai = 0; ai < NAI; ai++) acc[wi][ai] = vzero;

    auto stage = [&](auto BUFC, int kpos) {
        constexpr int nb = decltype(BUFC)::value;
        g2lds16(aP0 + kpos, &As[nb][(wave * 2 + 0) * 512]);
        g2lds16(aP1 + kpos, &As[nb][(wave * 2 + 1) * 512]);
        g2lds16(bP0 + kpos, &Bs[nb][(wave * 2 + 0) * 512]);
        g2lds16(bP1 + kpos, &Bs[nb][(wave * 2 + 1) * 512]);
    };
    auto gstep = [&](auto BUFC, int kpos, bool pref) {
        constexpr int buf = decltype(BUFC)::value;
        __syncthreads();
        if (pref) stage(IC<buf ^ 1>{}, kpos + 32);
        v8bf wf[4], af[NAI];
#pragma unroll
        for (int i = 0; i < 4; i++) wf[i] = *(const v8bf*)(&Bs[buf][fw + i * 512]);
#pragma unroll
        for (int i = 0; i < NAI; i++) af[i] = *(const v8bf*)(&As[buf][fa + i * 512]);
#pragma unroll
        for (int wi = 0; wi < 4; wi++)
#pragma unroll
            for (int ai = 0; ai < NAI; ai++)
                acc[wi][ai] = __builtin_amdgcn_mfma_f32_16x16x32_bf16(wf[wi], af[ai],
                                                                     acc[wi][ai], 0, 0, 0);
    };

    stage(IC<0>{}, 0);
#pragma unroll 1
    for (int k0 = 0; k0 < K; k0 += 64) {
        gstep(IC<0>{}, k0, true);
        gstep(IC<1>{}, k0 + 32, k0 + 64 < K);
    }

#pragma unroll
    for (int wi = 0; wi < 4; wi++) {
#pragma unroll
        for (int ai = 0; ai < NAI; ai++) {
            const long Nb = nb0 + noff + wi * 16 + kq * 4;
            const long M = m0 + moff + ai * 16 + n16;
            float4 b4 = *(const float4*)(&bias[Nb]);
            union { uint2 u2; unsigned short us[4]; } pk;
#pragma unroll
            for (int r = 0; r < 4; r++) {
                float t = acc[wi][ai][r] + ((const float*)&b4)[r];
                // tanh-form GELU via exp2+rcp (~7 VALU vs erff ~40)
                float y = t * (-2.302118131f + t * t * -0.1029433585f);
                float gl = t * fastrcp(1.f + __builtin_amdgcn_exp2f(y));
                pk.us[r] = f2bf(gl);
            }
            *(uint2*)(&outB[M * 3072 + Nb]) = pk.u2;
        }
    }
}

// ------------- split-K GEMM, 512 thr, 2 K-groups, 128x128 tile ---------------
// R8-proven. Waves 0-3 K-half 0 / waves 4-7 K-half 1 (own staging, 64KB,
// launch_bounds(512,4) -> VGPR cap 128, no acc spill). Group-1 accs pass
// through the dead staging LDS; group-0 adds partials + epilogue.
// EPI=0: QKV scatter + QSCALE + V^T FUSED (writes V directly in attn's
// [kt][64d][64k] tiled layout -- deletes the vtrans pass). EPI=1: bias+resid.
template <int EPI>
__global__ __launch_bounds__(512, 4) void gemm_splitk_kernel(
    const unsigned short* __restrict__ A, const unsigned short* __restrict__ Bt, int K,
    int Nt, const float* __restrict__ bias, const float* __restrict__ resid,
    float* __restrict__ outF, unsigned short* __restrict__ Qb,
    unsigned short* __restrict__ Kb, unsigned short* __restrict__ Vb) {
    __shared__ __align__(16) unsigned short SH[32768];   // 64KB
    const int tid = threadIdx.x;
    const int wave = tid >> 6, lane = tid & 63;
    const int kg = wave >> 2, wv = wave & 3;
    const int n16 = lane & 15, kq = lane >> 4;
    const int moff = (wv >> 1) * 64, noff = (wv & 1) * 64;
    const int id = blockIdx.x;
    const int xcd = id & 7, s = id >> 3;
    const int mt = xcd * 8 + s / Nt, nt_ = s % Nt;
    const long m0 = (long)mt * 128, nb0 = (long)nt_ * 128;
    const int Kh = K >> 1;

    const int c0 = (wv * 2 + 0) * 64 + lane;
    const int c1 = (wv * 2 + 1) * 64 + lane;
    const int r0 = c0 >> 2, r1 = c1 >> 2;
    const int kb = kg * Kh;
    const unsigned short* bP0 = Bt + (nb0 + r0) * K + ((((c0 & 3) ^ sg(r0)) << 3) + kb);
    const unsigned short* bP1 = Bt + (nb0 + r1) * K + ((((c1 & 3) ^ sg(r1)) << 3) + kb);
    const unsigned short* aP0 = A + (m0 + r0) * K + ((((c0 & 3) ^ sg(r0)) << 3) + kb);
    const unsigned short* aP1 = A + (m0 + r1) * K + ((((c1 & 3) ^ sg(r1)) << 3) + kb);
    const int sn = sg(n16);
    const int fw = (noff + n16) * 32 + ((kq ^ sn) << 3);
    const int fa = (moff + n16) * 32 + ((kq ^ sn) << 3);
    const int abase = kg * 8192, bbase = 16384 + kg * 8192;

    const v4f vzero = {0.f, 0.f, 0.f, 0.f};
    v4f acc[4][4];
#pragma unroll
    for (int wi = 0; wi < 4; wi++)
#pragma unroll
        for (int ai = 0; ai < 4; ai++) acc[wi][ai] = vzero;

    auto stage = [&](auto BUFC, int kpos) {
        constexpr int nb = decltype(BUFC)::value;
        unsigned short* asb = SH + abase + nb * 4096;
        unsigned short* bsb = SH + bbase + nb * 4096;
        g2lds16(aP0 + kpos, asb + (wv * 2 + 0) * 512);
        g2lds16(aP1 + kpos, asb + (wv * 2 + 1) * 512);
        g2lds16(bP0 + kpos, bsb + (wv * 2 + 0) * 512);
        g2lds16(bP1 + kpos, bsb + (wv * 2 + 1) * 512);
    };
    auto gstep = [&](auto BUFC, int kpos, bool pref) {
        constexpr int buf = decltype(BUFC)::value;
        __syncthreads();
        if (pref) stage(IC<buf ^ 1>{}, kpos + 32);
        const unsigned short* asb = SH + abase + buf * 4096;
        const unsigned short* bsb = SH + bbase + buf * 4096;
        v8bf wf[4], af[4];
#pragma unroll
        for (int i = 0; i < 4; i++) wf[i] = *(const v8bf*)(bsb + fw + i * 512);
#pragma unroll
        for (int i = 0; i < 4; i++) af[i] = *(const v8bf*)(asb + fa + i * 512);
#pragma unroll
        for (int wi = 0; wi < 4; wi++)
#pragma unroll
            for (int ai = 0; ai < 4; ai++)
                acc[wi][ai] = __builtin_amdgcn_mfma_f32_16x16x32_bf16(wf[wi], af[ai],
                                                                     acc[wi][ai], 0, 0, 0);
    };

    stage(IC<0>{}, 0);
#pragma unroll 1
    for (int k0 = 0; k0 < Kh; k0 += 64) {
        gstep(IC<0>{}, k0, true);
        gstep(IC<1>{}, k0 + 32, k0 + 64 < Kh);
    }

    // cross-group reduction through the (now dead) staging LDS: 4096 v4f = 64KB
    __syncthreads();                       // all frag reads of SH done
    v4f* ex = (v4f*)SH;
    if (kg == 1) {
#pragma unroll
        for (int wi = 0; wi < 4; wi++)
#pragma unroll
            for (int ai = 0; ai < 4; ai++)
                ex[((wv * 16 + wi * 4 + ai) << 6) + lane] = acc[wi][ai];
    }
    __syncthreads();
    if (kg == 1) return;

#pragma unroll
    for (int wi = 0; wi < 4; wi++) {
#pragma unroll
        for (int ai = 0; ai < 4; ai++) {
            v4f p = ex[((wv * 16 + wi * 4 + ai) << 6) + lane];
            const long Nb = nb0 + noff + wi * 16 + kq * 4;
            const long M = m0 + moff + ai * 16 + n16;
            if (EPI == 0) {
                int which = (int)(Nb / 768);
                int c = (int)(Nb - which * 768);
                int hh = c >> 6, ii = c & 63;
                int bb = (int)(M >> 12), t = (int)(M & 4095);
                if (which == 2) {
                    // V^T fused: [bh][kt][64d][64k] tiled layout (attn-ready).
                    // lanes n16 = 16 consecutive t -> contiguous 32B runs per d.
                    size_t basev = ((size_t)bb * N_HEAD + hh) * T_SEQ * D_HEAD;
                    size_t dstv = basev + (size_t)(t >> 6) * 4096 +
                                  (size_t)ii * 64 + (t & 63);
#pragma unroll
                    for (int r = 0; r < 4; r++)
                        Vb[dstv + r * 64] = f2bf(acc[wi][ai][r] + p[r]);
                } else {
                    size_t dst = (((size_t)bb * N_HEAD + hh) * T_SEQ + t) * D_HEAD + ii;
                    union { uint2 u2; unsigned short us[4]; } pk;
#pragma unroll
                    for (int r = 0; r < 4; r++) {
                        float v = acc[wi][ai][r] + p[r];
                        if (which == 0) v *= QSCALE;
                        pk.us[r] = f2bf(v);
                    }
                    if (which == 0) *(uint2*)(&Qb[dst]) = pk.u2;
                    else *(uint2*)(&Kb[dst]) = pk.u2;
                }
            } else {
                float4 b4 = *(const float4*)(&bias[Nb]);
                float4 r4 = *(const float4*)(&resid[M * 768 + Nb]);
                float4 o4;
                o4.x = acc[wi][ai][0] + p[0] + b4.x + r4.x;
                o4.y = acc[wi][ai][1] + p[1] + b4.y + r4.y;
                o4.z = acc[wi][ai][2] + p[2] + b4.z + r4.z;
                o4.w = acc[wi][ai][3] + p[3] + b4.w + r4.w;
                *(float4*)(&outF[M * 768 + Nb]) = o4;
            }
        }
    }
}

// ---------------- Flash attention (causal), bf16 Q/K/Vt -> bf16 y ------------
// R9-proven: 512-thread blocks, 8 waves x 16 q = 128 q-rows per block sharing
// ONE K/V staging. S^T trick, pre-scaled Q, l via ones-MFMA, P in registers
// via permlane32/16_swap -> exact K32 A-frags, setprio around MFMA clusters.
__global__ __launch_bounds__(512) void attn_kernel(const unsigned short* __restrict__ Q,
                                                   const unsigned short* __restrict__ Kg,
                                                   const unsigned short* __restrict__ Vt,
                                                   unsigned short* __restrict__ y) {
    __shared__ unsigned short Kt[2][4096];
    __shared__ unsigned short Vl[2][4096];
    const int tid = threadIdx.x;
    const int wave = tid >> 6, lane = tid & 63;
    const int n16 = lane & 15, kq = lane >> 4;
    const int id = blockIdx.x;
    const int xcd = id & 7, slot = id >> 3;           // slot 0..95
    const int combo = xcd * 3 + (slot % 3);           // 3 bh-combos per XCD
    const int qt2 = 31 - slot / 3;                    // longest blocks first
    const int h = combo % N_HEAD, b = combo / N_HEAD;
    const size_t hoff = (((size_t)b * N_HEAD + h) * T_SEQ) * D_HEAD;
    const unsigned short* Qh = Q + hoff;
    const unsigned short* Kh = Kg + hoff;   // [t][64], k-tile contiguous 8KB
    const unsigned short* Vh = Vt + hoff;   // [kt][64][64] tiled
    const v4f vzero = {0.f, 0.f, 0.f, 0.f};

    // staging: 8 waves x 1 chunk/lane per tile (512 chunks of 16B each)
    const int sC = wave * 64 + lane;
    const int soff = (sC >> 3) * 64 + ((((sC & 7) ^ ((sC >> 3) & 7))) << 3);
    const int fb0 = n16 * 64 + ((kq ^ (n16 & 7)) << 3);
    const int fb1 = n16 * 64 + (((4 + kq) ^ (n16 & 7)) << 3);
    v8bf vone;
#pragma unroll
    for (int j = 0; j < 8; j++) ((unsigned short*)&vone)[j] = 0x3F80;  // bf16 1.0

    const int qglob = qt2 * 128 + wave * 16 + n16;
    v8bf qf[2];
#pragma unroll
    for (int ks = 0; ks < 2; ks++)
        qf[ks] = *(const v8bf*)(&Qh[(size_t)qglob * D_HEAD + ks * 32 + kq * 8]);

    v4f o[4], lacc;
#pragma unroll
    for (int nt = 0; nt < 4; nt++) o[nt] = vzero;
    lacc = vzero;

    const unsigned short* knext;
    const unsigned short* vnext;

    auto step = [&](auto BUFC, int kt, bool pref, bool diag) {
        constexpr int buf = decltype(BUFC)::value;
        __syncthreads();  // buf's tiles ready (vmcnt), prev reads done (lgkm)
        if (pref) {
            g2lds16(knext + soff, &Kt[buf ^ 1][wave * 512]);
            g2lds16(vnext + soff, &Vl[buf ^ 1][wave * 512]);
            knext += 4096;
            vnext += 4096;
        }
        v4f s[4];
#pragma unroll
        for (int nt = 0; nt < 4; nt++) s[nt] = vzero;
        __builtin_amdgcn_s_setprio(1);
#pragma unroll
        for (int nt = 0; nt < 4; nt++) {
            v8bf k0 = *(const v8bf*)(&Kt[buf][nt * 1024 + fb0]);
            v8bf k1 = *(const v8bf*)(&Kt[buf][nt * 1024 + fb1]);
            s[nt] = __builtin_amdgcn_mfma_f32_16x16x32_bf16(k0, qf[0], s[nt], 0, 0, 0);
            s[nt] = __builtin_amdgcn_mfma_f32_16x16x32_bf16(k1, qf[1], s[nt], 0, 0, 0);
        }
        __builtin_amdgcn_s_setprio(0);
        // exp2 + bf16 pack; pa[ntk] = P[keys ntk*16+4kq..+3][q=n16]
        union PW { v4s s4; unsigned u[2]; } pa[4];
#pragma unroll
        for (int ntk = 0; ntk < 4; ntk++) {
            union { v4s s4; __bf16 h[4]; } pk;
#pragma unroll
            for (int r = 0; r < 4; r++) {
                float p = __builtin_amdgcn_exp2f(s[ntk][r]);
                if (diag) {
                    int key = kt * 64 + ntk * 16 + kq * 4 + r;
                    if (key > qglob) p = 0.f;
                }
                pk.h[r] = (__bf16)p;
            }
            pa[ntk].s4 = pk.s4;
        }
        // permlane exchange: build K32 A-frags pf[ks] (lane: P^T[q=n16]
        // [keys ks*32+kq*8..+7]). For word j: 32swap gathers {u01,v01}/{u23,v23},
        // 16swap gathers even/odd rows -> W_j and W_{j+2}.
        union F8 { v8bf v; unsigned u[4]; } pf[2];
#pragma unroll
        for (int ks = 0; ks < 2; ks++) {
#pragma unroll
            for (int j = 0; j < 2; j++) {
                unsigned X = pa[2 * ks].u[j], Y = pa[2 * ks + 1].u[j];
                pl32swap(X, Y);
                pl16swap(X, Y);
                pf[ks].u[j] = X;
                pf[ks].u[j + 2] = Y;
            }
        }
        __builtin_amdgcn_s_setprio(1);
#pragma unroll
        for (int ks = 0; ks < 2; ks++) {
            lacc = __builtin_amdgcn_mfma_f32_16x16x32_bf16(pf[ks].v, vone, lacc, 0, 0, 0);
#pragma unroll
            for (int nt = 0; nt < 4; nt++) {
                v8bf vb = *(const v8bf*)(&Vl[buf][nt * 1024 + (ks ? fb1 : fb0)]);
                o[nt] = __builtin_amdgcn_mfma_f32_16x16x32_bf16(pf[ks].v, vb, o[nt], 0, 0, 0);
            }
        }
        __builtin_amdgcn_s_setprio(0);
    };

    // prologue: stage kt=0 into buf0 (first step's barrier drains vmcnt)
    g2lds16(Kh + soff, &Kt[0][wave * 512]);
    g2lds16(Vh + soff, &Vl[0][wave * 512]);
    knext = Kh + 4096;
    vnext = Vh + 4096;

    const int nst = 2 * qt2 + 2;   // always even
    int kt = 0;
#pragma unroll 1
    while (kt < nst - 2) {
        step(IC<0>{}, kt, true, false);
        step(IC<1>{}, kt + 1, true, false);
        kt += 2;
    }
    step(IC<0>{}, kt, true, true);       // prefetches tile nst-1
    step(IC<1>{}, kt + 1, false, true);  // waves 0-3 fully self-masked here

    float linv[4];
#pragma unroll
    for (int r = 0; r < 4; r++) linv[r] = fastrcp(lacc[r]);
#pragma unroll
    for (int nt = 0; nt < 4; nt++)
#pragma unroll
        for (int r = 0; r < 4; r++) {
            int q = qt2 * 128 + wave * 16 + kq * 4 + r;
            float val = o[nt][r] * linv[r];
            y[((size_t)b * T_SEQ + q) * D_EMB + h * 64 + nt * 16 + n16] = f2bf(val);
        }
}

// ---------------- launch -----------------------------------------------------
extern "C" void kernel_launch(void* const* d_in, const int* in_sizes, int n_in,
                              void* d_out, int out_size, void* d_ws, size_t ws_size,
                              hipStream_t stream) {
    const float* x = (const float*)d_in[0];
    const float* ln1_g = (const float*)d_in[1];
    const float* ln1_b = (const float*)d_in[2];
    const float* wqkv_w = (const float*)d_in[3];
    const float* wo_w = (const float*)d_in[4];
    const float* wo_b = (const float*)d_in[5];
    const float* ln2_g = (const float*)d_in[6];
    const float* ln2_b = (const float*)d_in[7];
    const float* w1_w = (const float*)d_in[8];
    const float* w1_b = (const float*)d_in[9];
    const float* w2_w = (const float*)d_in[10];
    const float* w2_b = (const float*)d_in[11];
    float* out = (float*)d_out;

    char* ws = (char*)d_ws;
    size_t off = 0;
    auto alloc = [&](size_t bytes) -> void* {
        void* p = ws + off;
        off += (bytes + 255) & ~(size_t)255;
        return p;
    };
    unsigned short* xn = (unsigned short*)alloc((size_t)NTOK * D_EMB * 2);
    unsigned short* wqkvT = (unsigned short*)alloc((size_t)2304 * 768 * 2);
    unsigned short* woT = (unsigned short*)alloc((size_t)768 * 768 * 2);
    unsigned short* w1T = (unsigned short*)alloc((size_t)3072 * 768 * 2);
    unsigned short* w2T = (unsigned short*)alloc((size_t)768 * 3072 * 2);
    unsigned short* Qb = (unsigned short*)alloc((size_t)NTOK * D_EMB * 2);
    unsigned short* Kb = (unsigned short*)alloc((size_t)NTOK * D_EMB * 2);
    unsigned short* Vb = (unsigned short*)alloc((size_t)NTOK * D_EMB * 2);  // V^T tiled
    unsigned short* yb = (unsigned short*)alloc((size_t)NTOK * D_EMB * 2);
    float* res1 = (float*)alloc((size_t)NTOK * D_EMB * 4);
    unsigned short* hbuf = Qb;  // w1 out overlay: spans Qb..yb (all dead then)

    dim3 tb(32, 8);
    tcast4_kernel<<<6912, tb, 0, stream>>>(wqkv_w, wqkvT, wo_w, woT,
                                           w1_w, w1T, w2_w, w2T);

    ln_kernel<<<NTOK, 256, 0, stream>>>(x, ln1_g, ln1_b, xn);

    gemm_splitk_kernel<0><<<1152, 512, 0, stream>>>(  // qkv + fused V^T
        xn, wqkvT, 768, 18, nullptr, nullptr, nullptr, Qb, Kb, Vb);

    attn_kernel<<<768, 512, 0, stream>>>(Qb, Kb, Vb, yb);

    gemm_splitk_kernel<1><<<384, 512, 0, stream>>>(   // wo: split-K=2
        yb, woT, 768, 6, wo_b, x, res1, nullptr, nullptr, nullptr);

    ln_kernel<<<NTOK, 256, 0, stream>>>(res1, ln2_g, ln2_b, xn);

    gemm_kernel<2, 128><<<1536, 256, 0, stream>>>(    // w1: 32KB, 5/CU (proven)
        xn, w1T, 768, 24, w1_b, hbuf);

    gemm_splitk_kernel<1><<<384, 512, 0, stream>>>(   // w2: split-K=2
        hbuf, w2T, 3072, 6, w2_b, res1, out, nullptr, nullptr, nullptr);
}